// Round 4
// baseline (276.771 us; speedup 1.0000x reference)
//
#include <hip/hip_runtime.h>

#define B_ 1024
#define D_ 512
#define T_ 36
#define NT_ 64
#define DS_ 32
#define DG_ 128   // D/G
#define EPS_ 1e-5f

typedef float f32x4 __attribute__((ext_vector_type(4)));
typedef __bf16 bf16x8 __attribute__((ext_vector_type(8)));
typedef unsigned short u16x8 __attribute__((ext_vector_type(8)));
typedef unsigned short u16x4 __attribute__((ext_vector_type(4)));

#define DEVI static __device__ __forceinline__

DEVI unsigned short f2bf(float f) { return __builtin_bit_cast(unsigned short, (__bf16)f); }
DEVI float bf2f(unsigned short h) { return (float)__builtin_bit_cast(__bf16, h); }

// swizzled byte offset: row-major tile, 16B-slot XOR swizzle (T2 pattern)
DEVI unsigned swz(int row, int pitchB, int col) {   // col in ushort elements
    return (unsigned)(row * pitchB + ((2 * col) ^ ((row & 7) << 4)));
}

// ---- K0: prepack tok bf16 [64][512] + block-diag wd bf16 [32][512] ----
__global__ __launch_bounds__(512)
void k0_prepack(const float* __restrict__ tok, const float* __restrict__ wd,
                unsigned short* __restrict__ tokbf, unsigned short* __restrict__ wdd)
{
    int i = blockIdx.x * 512 + threadIdx.x;
    if (i < NT_ * D_) {
        tokbf[i] = f2bf(tok[i]);
    } else {
        int j = i - NT_ * D_;                 // < 16384
        int o = j >> 9, dd = j & 511;
        wdd[j] = ((dd >> 7) == (o >> 3)) ? f2bf(wd[o * DG_ + (dd & 127)]) : (unsigned short)0;
    }
}

// stage [512][36] f32 -> LDS image [48 rows s][1024B] swizzled (rows 36..47 untouched)
DEVI void stage_T(const float* __restrict__ src, char* __restrict__ dst, int tid)
{
    if (tid < 576) {
        int dblk = tid / 9, s4 = tid - dblk * 9;
        int s0 = s4 * 4;
        const float* bp = src + dblk * 8 * T_ + s0;
        u16x8 u0, u1, u2, u3;
        #pragma unroll
        for (int r = 0; r < 8; ++r) {
            f32x4 v = *(const f32x4*)(bp + r * T_);
            u0[r] = f2bf(v[0]); u1[r] = f2bf(v[1]);
            u2[r] = f2bf(v[2]); u3[r] = f2bf(v[3]);
        }
        *(u16x8*)(dst + swz(s0 + 0, 1024, dblk * 8)) = u0;
        *(u16x8*)(dst + swz(s0 + 1, 1024, dblk * 8)) = u1;
        *(u16x8*)(dst + swz(s0 + 2, 1024, dblk * 8)) = u2;
        *(u16x8*)(dst + swz(s0 + 3, 1024, dblk * 8)) = u3;
    }
}

// =================== K1A: ysT -> G1 -> softmax1 -> G2 -> rep (2 global layouts) ===================
// LDS: ysT swz [48][1024B] @0 ; sc f32 [64][42] @49152 ; att1 u16 [64][72] @59904
#define K1A_LDS 69120
__global__ __launch_bounds__(1024, 8)
void k1a_attn(const float* __restrict__ y, const float* __restrict__ tokf,
              const unsigned short* __restrict__ tokbf,
              unsigned short* __restrict__ rep_base, int b0)
{
    extern __shared__ char lds[];
    float*          sc   = (float*)(lds + 49152);
    unsigned short* att1 = (unsigned short*)(lds + 59904);

    const int b    = b0 + blockIdx.x;
    const int tid  = threadIdx.x;
    const int lane = tid & 63;
    const int w    = tid >> 6;
    const int l15  = lane & 15;
    const int l4   = lane >> 4;

    const float* yb = y + b * (D_ * T_);
    unsigned short* rep_p = rep_base + (size_t)blockIdx.x * 65536;
    unsigned short* rep_t = rep_p + 32768;

    // threads >=576 zero pads while 0..575 stage
    if (tid >= 576) {
        int z = tid - 576;
        unsigned* zp = (unsigned*)(lds + 36 * 1024);
        for (int i = z; i < 3072; i += 448) zp[i] = 0u;
        unsigned* za = (unsigned*)att1;
        for (int i = z; i < 2304; i += 448) za[i] = 0u;
    }
    stage_T(yb, lds, tid);
    __syncthreads();

    // ---- G1: sc[t][s] = tok @ ys  (M=64,N=48,K=512) ----
    if (w < 12) {
        int mt = w & 3, nt = w >> 2;
        f32x4 acc = {0.f, 0.f, 0.f, 0.f};
        int trow = mt * 16 + l15, srow = nt * 16 + l15;
        for (int ks = 0; ks < 16; ++ks) {
            int k0 = ks * 32 + l4 * 8;
            bf16x8 af = *(const bf16x8*)(tokbf + trow * 512 + k0);
            bf16x8 bv = *(const bf16x8*)(lds + swz(srow, 1024, k0));
            acc = __builtin_amdgcn_mfma_f32_16x16x32_bf16(af, bv, acc, 0, 0, 0);
        }
        int s = srow;
        if (s < T_) {
            #pragma unroll
            for (int j = 0; j < 4; ++j)
                sc[(mt * 16 + l4 * 4 + j) * 42 + s] = acc[j];
        }
    }
    __syncthreads();

    // ---- softmax over s per t (t = tid>>4) ----
    {
        int t = tid >> 4, l16 = tid & 15;
        float v0 = sc[t * 42 + l16];
        float v1 = sc[t * 42 + l16 + 16];
        float v2 = (l16 < 4) ? sc[t * 42 + l16 + 32] : -1e30f;
        float m = fmaxf(fmaxf(v0, v1), v2);
        #pragma unroll
        for (int off = 1; off < 16; off <<= 1) m = fmaxf(m, __shfl_xor(m, off));
        float e0 = __expf(v0 - m), e1 = __expf(v1 - m);
        float e2 = (l16 < 4) ? __expf(v2 - m) : 0.f;
        float ssum = e0 + e1 + e2;
        #pragma unroll
        for (int off = 1; off < 16; off <<= 1) ssum += __shfl_xor(ssum, off);
        float inv = 1.f / ssum;
        att1[t * 72 + l16]      = f2bf(e0 * inv);
        att1[t * 72 + l16 + 16] = f2bf(e1 * inv);
        if (l16 < 4) att1[t * 72 + l16 + 32] = f2bf(e2 * inv);
    }
    __syncthreads();

    // ---- G2: rep[t][d] = tok + att1 @ ys^T (K=s, B from global y native) ----
    {
        int mt = w >> 2;
        int trow = mt * 16 + l15;
        bf16x8 a0 = *(const bf16x8*)&att1[trow * 72 + l4 * 8];
        bf16x8 a1 = *(const bf16x8*)&att1[trow * 72 + 32 + l4 * 8];
        int tbr = mt * 16 + l4 * 4;
        int ntB = (w & 3) * 8;
        for (int nt = ntB; nt < ntB + 8; ++nt) {
            int d = nt * 16 + l15;
            const float* yrow = yb + d * T_;
            f32x4 p0 = *(const f32x4*)(yrow + l4 * 8);
            f32x4 p1 = *(const f32x4*)(yrow + l4 * 8 + 4);
            f32x4 p2 = *(const f32x4*)(yrow + 32);   // tail; paired att1 cols >=36 are zero
            bf16x8 fb0, fb1;
            #pragma unroll
            for (int j = 0; j < 4; ++j) {
                fb0[j] = (__bf16)p0[j]; fb0[4 + j] = (__bf16)p1[j];
                fb1[j] = (__bf16)p2[j]; fb1[4 + j] = fb1[j];
            }
            f32x4 acc = {0.f, 0.f, 0.f, 0.f};
            acc = __builtin_amdgcn_mfma_f32_16x16x32_bf16(a0, fb0, acc, 0, 0, 0);
            acc = __builtin_amdgcn_mfma_f32_16x16x32_bf16(a1, fb1, acc, 0, 0, 0);
            u16x4 pk;
            #pragma unroll
            for (int j = 0; j < 4; ++j) {
                float val = tokf[(tbr + j) * 512 + d] + acc[j];
                unsigned short hv = f2bf(val);
                rep_p[(tbr + j) * 512 + d] = hv;
                pk[j] = hv;
            }
            *(u16x4*)(rep_t + d * 64 + tbr) = pk;
        }
    }
}

// =================== K1B: xsT -> G3 -> softmax2 -> G4 -> LN -> MFMA downconv ===================
// LDS: xsT swz [48][1024B] @0 (h overlay after G4) ; sc f32 [64][42] @49152 (red overlay) ; att2 u16 [48][72] @59904
#define K1B_LDS 66816
__global__ __launch_bounds__(1024, 8)
void k1b_attn(const float* __restrict__ x, const unsigned short* __restrict__ rep_base,
              const float* __restrict__ gav_p, const unsigned short* __restrict__ wdd,
              const float* __restrict__ lnbg, const float* __restrict__ lnbb,
              float* __restrict__ z_pre, int b0)
{
    extern __shared__ char lds[];
    float*          sc   = (float*)(lds + 49152);
    float*          red  = sc;
    unsigned short* att2 = (unsigned short*)(lds + 59904);

    const int b    = b0 + blockIdx.x;
    const int tid  = threadIdx.x;
    const int lane = tid & 63;
    const int w    = tid >> 6;
    const int l15  = lane & 15;
    const int l4   = lane >> 4;

    const float* xb = x + b * (D_ * T_);
    const unsigned short* rep_p = rep_base + (size_t)blockIdx.x * 65536;
    const unsigned short* rep_t = rep_p + 32768;

    if (tid >= 576) {
        int z = tid - 576;
        unsigned* zp = (unsigned*)(lds + 36 * 1024);
        for (int i = z; i < 3072; i += 448) zp[i] = 0u;
        unsigned* za = (unsigned*)att2;
        for (int i = z; i < 1728; i += 448) za[i] = 0u;
    }
    stage_T(xb, lds, tid);
    __syncthreads();

    // ---- G3: sc[t][s] = rep @ xs  (A = rep_plain global, B = xsT LDS) ----
    if (w < 12) {
        int mt = w & 3, nt = w >> 2;
        f32x4 acc = {0.f, 0.f, 0.f, 0.f};
        int trow = mt * 16 + l15, srow = nt * 16 + l15;
        for (int ks = 0; ks < 16; ++ks) {
            int k0 = ks * 32 + l4 * 8;
            bf16x8 af = *(const bf16x8*)(rep_p + trow * 512 + k0);
            bf16x8 bv = *(const bf16x8*)(lds + swz(srow, 1024, k0));
            acc = __builtin_amdgcn_mfma_f32_16x16x32_bf16(af, bv, acc, 0, 0, 0);
        }
        int s = srow;
        if (s < T_) {
            #pragma unroll
            for (int j = 0; j < 4; ++j)
                sc[(mt * 16 + l4 * 4 + j) * 42 + s] = acc[j];
        }
    }
    __syncthreads();

    // ---- softmax over t per s ----
    if (tid < 576) {
        int s = tid >> 4, l16 = tid & 15;
        float v0 = sc[(l16     ) * 42 + s];
        float v1 = sc[(l16 + 16) * 42 + s];
        float v2 = sc[(l16 + 32) * 42 + s];
        float v3 = sc[(l16 + 48) * 42 + s];
        float m = fmaxf(fmaxf(v0, v1), fmaxf(v2, v3));
        #pragma unroll
        for (int off = 1; off < 16; off <<= 1) m = fmaxf(m, __shfl_xor(m, off));
        float e0 = __expf(v0 - m), e1 = __expf(v1 - m), e2 = __expf(v2 - m), e3 = __expf(v3 - m);
        float ssum = e0 + e1 + e2 + e3;
        #pragma unroll
        for (int off = 1; off < 16; off <<= 1) ssum += __shfl_xor(ssum, off);
        float inv = 1.f / ssum;
        att2[s * 72 + l16]      = f2bf(e0 * inv);
        att2[s * 72 + l16 + 16] = f2bf(e1 * inv);
        att2[s * 72 + l16 + 32] = f2bf(e2 * inv);
        att2[s * 72 + l16 + 48] = f2bf(e3 * inv);
    }
    __syncthreads();

    // ---- G4: x_res[s][d] = att2 @ rep (A = att2 LDS, B = repT global) + xc + LN -> h ----
    {
        const float gav = gav_p[0];
        f32x4 acc[3][2];
        #pragma unroll
        for (int m = 0; m < 3; ++m)
            #pragma unroll
            for (int n = 0; n < 2; ++n) acc[m][n] = (f32x4){0.f, 0.f, 0.f, 0.f};

        #pragma unroll
        for (int ks = 0; ks < 2; ++ks) {
            int t0 = ks * 32 + l4 * 8;
            bf16x8 af[3];
            #pragma unroll
            for (int m = 0; m < 3; ++m)
                af[m] = *(const bf16x8*)&att2[(m * 16 + l15) * 72 + t0];
            #pragma unroll
            for (int n = 0; n < 2; ++n) {
                int d = (2 * w + n) * 16 + l15;
                bf16x8 bv = *(const bf16x8*)(rep_t + d * 64 + t0);
                #pragma unroll
                for (int m = 0; m < 3; ++m)
                    acc[m][n] = __builtin_amdgcn_mfma_f32_16x16x32_bf16(af[m], bv, acc[m][n], 0, 0, 0);
            }
        }

        // xc = xs + gav*x_res ; per-s LN partials
        #pragma unroll
        for (int m = 0; m < 3; ++m) {
            #pragma unroll
            for (int j = 0; j < 4; ++j) {
                int s = m * 16 + l4 * 4 + j;
                if (s < T_) {
                    float rsum = 0.f, rsq = 0.f;
                    #pragma unroll
                    for (int n = 0; n < 2; ++n) {
                        int d = (2 * w + n) * 16 + l15;
                        float xsv = bf2f(*(const unsigned short*)(lds + swz(s, 1024, d)));
                        float xc = xsv + gav * acc[m][n][j];
                        acc[m][n][j] = xc;
                        rsum += xc; rsq += xc * xc;
                    }
                    #pragma unroll
                    for (int off = 1; off < 16; off <<= 1) {
                        rsum += __shfl_xor(rsum, off);
                        rsq  += __shfl_xor(rsq, off);
                    }
                    if (l15 == 0) {
                        red[s * 32 + w * 2 + 0] = rsum;
                        red[s * 32 + w * 2 + 1] = rsq;
                    }
                }
            }
        }
        __syncthreads();
        if (tid < T_) {
            int s = tid;
            float S = 0.f, Q = 0.f;
            #pragma unroll
            for (int q = 0; q < 16; ++q) { S += red[s * 32 + q * 2]; Q += red[s * 32 + q * 2 + 1]; }
            float mu = S * (1.f / 512.f);
            float var = Q * (1.f / 512.f) - mu * mu;
            red[1152 + s] = mu;
            red[1200 + s] = rsqrtf(var + EPS_);
        }
        __syncthreads();

        // h (bf16) overlays xsT rows 0..35 (rows 36..47 stay zero for MFMA pad)
        float lg[2], lb[2];
        #pragma unroll
        for (int n = 0; n < 2; ++n) {
            int d = (2 * w + n) * 16 + l15;
            lg[n] = lnbg[d]; lb[n] = lnbb[d];
        }
        #pragma unroll
        for (int m = 0; m < 3; ++m) {
            #pragma unroll
            for (int j = 0; j < 4; ++j) {
                int s = m * 16 + l4 * 4 + j;
                if (s < T_) {
                    float mu = red[1152 + s], rs = red[1200 + s];
                    #pragma unroll
                    for (int n = 0; n < 2; ++n) {
                        int d = (2 * w + n) * 16 + l15;
                        *(unsigned short*)(lds + swz(s, 1024, d)) =
                            f2bf((acc[m][n][j] - mu) * rs * lg[n] + lb[n]);
                    }
                }
            }
        }
    }
    __syncthreads();

    // ---- grouped down conv via MFMA: z[o][s] = wdd(blockdiag) @ h  (M=32,N=48,K=512) ----
    if (w < 6) {
        int mt = w >> 1;          // hmm: need mt in 0..1, nt in 0..2
        int nt = w - mt * 2;      // placeholder; fixed below
        mt = w / 3; nt = w - mt * 3;
        f32x4 acc = {0.f, 0.f, 0.f, 0.f};
        int orow = mt * 16 + l15, srow = nt * 16 + l15;
        for (int ks = 0; ks < 16; ++ks) {
            int k0 = ks * 32 + l4 * 8;
            bf16x8 af = *(const bf16x8*)(wdd + orow * 512 + k0);
            bf16x8 bv = *(const bf16x8*)(lds + swz(srow, 1024, k0));
            acc = __builtin_amdgcn_mfma_f32_16x16x32_bf16(af, bv, acc, 0, 0, 0);
        }
        int s = srow;
        if (s < T_) {
            #pragma unroll
            for (int j = 0; j < 4; ++j)
                z_pre[b * (DS_ * T_) + (mt * 16 + l4 * 4 + j) * T_ + s] = acc[j];
        }
    }
}

// ---- K3: bn1 stats, two-level ----
__global__ __launch_bounds__(256)
void k3a_bn1part(const float* __restrict__ z_pre, float* __restrict__ p3)
{
    __shared__ float rbuf[4][2];
    int blk = blockIdx.x;
    int o = blk & 31, sl = blk >> 5;
    int tid = threadIdx.x;
    float S = 0.f, Q = 0.f;
    for (int i = tid; i < 64 * T_; i += 256) {
        int bb = sl * 64 + i / T_, t = i - (i / T_) * T_;
        float v = z_pre[bb * (DS_ * T_) + o * T_ + t];
        S += v; Q += v * v;
    }
    #pragma unroll
    for (int off = 1; off < 64; off <<= 1) { S += __shfl_xor(S, off); Q += __shfl_xor(Q, off); }
    int ww = tid >> 6;
    if ((tid & 63) == 0) { rbuf[ww][0] = S; rbuf[ww][1] = Q; }
    __syncthreads();
    if (tid == 0) {
        float s2 = 0.f, q2 = 0.f;
        for (int i = 0; i < 4; ++i) { s2 += rbuf[i][0]; q2 += rbuf[i][1]; }
        p3[blk * 2] = s2; p3[blk * 2 + 1] = q2;
    }
}

__global__ __launch_bounds__(64)
void k3b_bn1stats(const float* __restrict__ p3, float* __restrict__ st1)
{
    int o = threadIdx.x;
    if (o < 32) {
        float S = 0.f, Q = 0.f;
        for (int sl = 0; sl < 16; ++sl) {
            S += p3[((sl << 5) | o) * 2];
            Q += p3[((sl << 5) | o) * 2 + 1];
        }
        float mu = S / 36864.f;
        float var = Q / 36864.f - mu * mu;
        st1[o] = mu; st1[32 + o] = rsqrtf(var + EPS_);
    }
}

// ---- K4M: per-group 8x8 second-moment partials of zr = relu(bn1(z)) ----
__global__ __launch_bounds__(256)
void k4m_moments(const float* __restrict__ z_pre, const float* __restrict__ st1,
                 const float* __restrict__ g1p, const float* __restrict__ b1p,
                 float* __restrict__ m4)
{
    __shared__ float zr[32][40];
    int blk = blockIdx.x, tid = threadIdx.x;
    int c2 = tid & 7, c1 = (tid >> 3) & 7, g = tid >> 6;
    int ch1 = g * 8 + c1, ch2 = g * 8 + c2;
    float acc = 0.f, asum = 0.f;
    for (int bi = 0; bi < 16; ++bi) {
        int b = blk * 16 + bi;
        __syncthreads();
        for (int i = tid; i < DS_ * T_; i += 256) {
            int o = i / T_, t = i - o * T_;
            float v = z_pre[b * (DS_ * T_) + i];
            zr[o][t] = fmaxf(0.f, (v - st1[o]) * st1[32 + o] * g1p[o] + b1p[o]);
        }
        __syncthreads();
        for (int t = 0; t < T_; ++t) {
            float a = zr[ch1][t], b2 = zr[ch2][t];
            acc += a * b2;
            asum += a;
        }
    }
    m4[blk * 288 + tid] = acc;
    if (c1 == c2) m4[blk * 288 + 256 + g * 8 + c1] = asum;
}

// ---- K4S: reduce moments -> bn2 stats via E[o^2] = w^T M w ----
__global__ __launch_bounds__(512)
void k4s_bn2stats(const float* __restrict__ m4, const float* __restrict__ wu,
                  float* __restrict__ st2)
{
    __shared__ float M2[256], mz[32];
    int tid = threadIdx.x;
    if (tid < 256) {
        float S = 0.f;
        for (int k = 0; k < 64; ++k) S += m4[k * 288 + tid];
        M2[tid] = S * (1.f / 36864.f);
    } else if (tid < 288) {
        int j = tid - 256;
        float S = 0.f;
        for (int k = 0; k < 64; ++k) S += m4[k * 288 + 256 + j];
        mz[j] = S * (1.f / 36864.f);
    }
    __syncthreads();
    int d = tid, g = d >> 7;
    float wr[8];
    #pragma unroll
    for (int c = 0; c < 8; ++c) wr[c] = wu[d * 8 + c];
    float mu2 = 0.f;
    #pragma unroll
    for (int c = 0; c < 8; ++c) mu2 += wr[c] * mz[g * 8 + c];
    float e2 = 0.f;
    #pragma unroll
    for (int c = 0; c < 8; ++c)
        #pragma unroll
        for (int c2 = 0; c2 < 8; ++c2)
            e2 += wr[c] * wr[c2] * M2[g * 64 + c * 8 + c2];
    st2[d] = mu2;
    st2[512 + d] = rsqrtf(e2 - mu2 * mu2 + EPS_);
}

// ---- K5: up conv + bn2 + LN(lnp) + gate -> out ----
#define K5_LDS 47888
__global__ __launch_bounds__(512, 6)
void k5_final(const float* __restrict__ z_pre, const float* __restrict__ st1,
              const float* __restrict__ g1p, const float* __restrict__ b1p,
              const float* __restrict__ wu, const float* __restrict__ st2,
              const float* __restrict__ g2p, const float* __restrict__ b2p,
              const float* __restrict__ lnpg, const float* __restrict__ lnpb,
              const float* __restrict__ gate_p, float* __restrict__ out)
{
    extern __shared__ char lds[];
    unsigned short* o_f = (unsigned short*)lds;   // [512][41]
    float* zrT = (float*)(lds + 41984);           // [36][41]
    int b = blockIdx.x;
    int tid = threadIdx.x;

    for (int i = tid; i < DS_ * T_; i += 512) {
        int o = i / T_, s = i - o * T_;
        float v = z_pre[b * (DS_ * T_) + i];
        zrT[s * 41 + o] = fmaxf(0.f, (v - st1[o]) * st1[32 + o] * g1p[o] + b1p[o]);
    }
    __syncthreads();

    for (int i = tid; i < D_ * T_; i += 512) {
        int d = i / T_, t = i - d * T_;
        const float* zp = &zrT[t * 41 + (d >> 7) * 8];
        const float* wp = &wu[d * 8];
        f32x4 w0 = *(const f32x4*)wp;
        f32x4 w1 = *(const f32x4*)(wp + 4);
        float acc = zp[0]*w0[0] + zp[1]*w0[1] + zp[2]*w0[2] + zp[3]*w0[3]
                  + zp[4]*w1[0] + zp[5]*w1[1] + zp[6]*w1[2] + zp[7]*w1[3];
        o_f[d * 41 + t] = f2bf((acc - st2[d]) * st2[512 + d] * g2p[d] + b2p[d]);
    }
    __syncthreads();

    int w = tid >> 6, lane = tid & 63;
    float gate = gate_p[0];
    for (int t = w; t < T_; t += 8) {
        float S = 0.f, Q = 0.f;
        float v[8];
        #pragma unroll
        for (int i2 = 0; i2 < 8; ++i2) {
            float vv = bf2f(o_f[(i2 * 64 + lane) * 41 + t]);
            v[i2] = vv; S += vv; Q += vv * vv;
        }
        #pragma unroll
        for (int off = 1; off < 64; off <<= 1) { S += __shfl_xor(S, off); Q += __shfl_xor(Q, off); }
        float mu = S * (1.f / 512.f);
        float var = Q * (1.f / 512.f) - mu * mu;
        float rs = rsqrtf(var + EPS_);
        #pragma unroll
        for (int i2 = 0; i2 < 8; ++i2) {
            int d = i2 * 64 + lane;
            o_f[d * 41 + t] = f2bf(gate * ((v[i2] - mu) * rs * lnpg[d] + lnpb[d]));
        }
    }
    __syncthreads();

    float* ob = out + b * (D_ * T_);
    for (int i = tid; i < D_ * T_; i += 512) {
        int d = i / T_, t = i - d * T_;
        ob[i] = bf2f(o_f[d * 41 + t]);
    }
}

extern "C" void kernel_launch(void* const* d_in, const int* in_sizes, int n_in,
                              void* d_out, int out_size, void* d_ws, size_t ws_size,
                              hipStream_t stream)
{
    (void)in_sizes; (void)n_in; (void)out_size;
    const float* x    = (const float*)d_in[0];
    const float* y    = (const float*)d_in[1];
    const float* tok  = (const float*)d_in[2];
    const float* gate = (const float*)d_in[3];
    const float* gav  = (const float*)d_in[4];
    const float* wd   = (const float*)d_in[5];
    const float* wu   = (const float*)d_in[6];
    const float* bn1g = (const float*)d_in[7];
    const float* bn1b = (const float*)d_in[8];
    const float* bn2g = (const float*)d_in[9];
    const float* bn2b = (const float*)d_in[10];
    const float* lnbg = (const float*)d_in[11];
    const float* lnbb = (const float*)d_in[12];
    const float* lnpg = (const float*)d_in[13];
    const float* lnpb = (const float*)d_in[14];
    float* out = (float*)d_out;

    char* ws = (char*)d_ws;
    float* z_pre          = (float*)ws;                      // 4,718,592
    float* st1            = (float*)(ws + 4718592);          // 512
    unsigned short* tokbf = (unsigned short*)(ws + 4719104); // 65,536
    unsigned short* wdd   = (unsigned short*)(ws + 4784640); // 32,768
    float* p3             = (float*)(ws + 4817408);          // 4,096
    float* m4             = (float*)(ws + 4821504);          // 73,728
    float* st2            = (float*)(ws + 4895232);          // 4,096
    unsigned short* rep   = (unsigned short*)(ws + 4899328); // 131,072/batch

    size_t avail = (ws_size > 4899328) ? (ws_size - 4899328) : 131072;
    int bchunk = (int)(avail / 131072);
    if (bchunk < 1) bchunk = 1;
    if (bchunk > B_) bchunk = B_;

    hipFuncSetAttribute((const void*)k1a_attn, hipFuncAttributeMaxDynamicSharedMemorySize, K1A_LDS);
    hipFuncSetAttribute((const void*)k1b_attn, hipFuncAttributeMaxDynamicSharedMemorySize, K1B_LDS);
    hipFuncSetAttribute((const void*)k5_final, hipFuncAttributeMaxDynamicSharedMemorySize, K5_LDS);

    k0_prepack<<<96, 512, 0, stream>>>(tok, wd, tokbf, wdd);
    for (int b0 = 0; b0 < B_; b0 += bchunk) {
        int cnt = (b0 + bchunk <= B_) ? bchunk : (B_ - b0);
        k1a_attn<<<cnt, 1024, K1A_LDS, stream>>>(y, tok, tokbf, rep, b0);
        k1b_attn<<<cnt, 1024, K1B_LDS, stream>>>(x, rep, gav, wdd, lnbg, lnbb, z_pre, b0);
    }
    k3a_bn1part<<<512, 256, 0, stream>>>(z_pre, p3);
    k3b_bn1stats<<<1, 64, 0, stream>>>(p3, st1);
    k4m_moments<<<64, 256, 0, stream>>>(z_pre, st1, bn1g, bn1b, m4);
    k4s_bn2stats<<<1, 512, 0, stream>>>(m4, wu, st2);
    k5_final<<<B_, 512, K5_LDS, stream>>>(z_pre, st1, bn1g, bn1b, wu, st2, bn2g, bn2b,
                                          lnpg, lnpb, gate, out);
}

// Round 5
// 201.276 us; speedup vs baseline: 1.3751x; 1.3751x over previous
//
#include <hip/hip_runtime.h>

#define B_ 1024
#define D_ 512
#define T_ 36
#define NT_ 64
#define DS_ 32
#define EPS_ 1e-5f

typedef float f32x4 __attribute__((ext_vector_type(4)));
typedef __bf16 bf16x8 __attribute__((ext_vector_type(8)));
typedef unsigned short u16x8 __attribute__((ext_vector_type(8)));

#define DEVI static __device__ __forceinline__
#define MFMA16 __builtin_amdgcn_mfma_f32_16x16x32_bf16

DEVI unsigned short f2bf(float f) { return __builtin_bit_cast(unsigned short, (__bf16)f); }
DEVI float bf2f(unsigned short h) { return (float)__builtin_bit_cast(__bf16, h); }

// XOR-swizzled byte offset inside a [48][1024B] transposed image (T2 pattern)
DEVI unsigned swz(int row, int col) {   // col in ushort elements (0..511)
    return (unsigned)(row * 1024 + ((2 * col) ^ ((row & 7) << 4)));
}

// ---- K1 LDS layout ----
#define OFF_YST 0        // ysT [48][1024B] swz ; h_sT overlay after G-phases
#define OFF_XST 49152    // xsT [48][1024B] swz
#define OFF_SC  98304    // sc f32 [64][42] ; red overlay in epilogue
#define OFF_A1  109056   // att1  u16 [64][72]
#define OFF_A1T 118272   // att1T u16 [48][72]
#define OFF_A2  125184   // att2  u16 [48][72]
#define OFF_GT  132096   // GramT u16 [48][72]
#define OFF_W   139008   // W     u16 [48][72]
#define K1_LDS  145920

// ---- K0: prepack tok bf16 [64][512], tokT bf16 [512][64], block-diag wd bf16 [32][512] ----
__global__ __launch_bounds__(512)
void k0_prepack(const float* __restrict__ tok, const float* __restrict__ wd,
                unsigned short* __restrict__ tokbf, unsigned short* __restrict__ tokT,
                unsigned short* __restrict__ wdd)
{
    int i = blockIdx.x * 512 + threadIdx.x;
    if (i < 32768) {
        tokbf[i] = f2bf(tok[i]);
    } else if (i < 65536) {
        int j = i - 32768; int d = j >> 6, t = j & 63;
        tokT[j] = f2bf(tok[t * 512 + d]);
    } else if (i < 81920) {
        int j = i - 65536; int o = j >> 9, dd = j & 511;
        wdd[j] = ((dd >> 7) == (o >> 3)) ? f2bf(wd[o * 128 + (dd & 127)]) : (unsigned short)0;
    }
}

// =================== K1: fused attention + LN + downconv (no rep materialization) ===================
__global__ __launch_bounds__(1024, 4)
void k1_fused(const float* __restrict__ x, const float* __restrict__ y,
              const unsigned short* __restrict__ tokbf, const unsigned short* __restrict__ tokT,
              const float* __restrict__ gav_p, const unsigned short* __restrict__ wdd,
              const float* __restrict__ lnbg, const float* __restrict__ lnbb,
              float* __restrict__ z_pre)
{
    extern __shared__ char lds[];
    float* sc = (float*)(lds + OFF_SC);
    unsigned short* a1  = (unsigned short*)(lds + OFF_A1);
    unsigned short* a1t = (unsigned short*)(lds + OFF_A1T);
    unsigned short* a2  = (unsigned short*)(lds + OFF_A2);
    unsigned short* gt  = (unsigned short*)(lds + OFF_GT);
    unsigned short* wb  = (unsigned short*)(lds + OFF_W);

    const int b    = blockIdx.x;
    const int tid  = threadIdx.x;
    const int lane = tid & 63;
    const int w    = tid >> 6;   // 0..15
    const int l15  = lane & 15;
    const int l4   = lane >> 4;  // 0..3

    const float* yb = y + b * (D_ * T_);
    const float* xb = x + b * (D_ * T_);

    // ---- P0: zero pads (ysT/xsT rows 36..47; all small matrices A1..W contiguous) ----
    {
        unsigned* z1 = (unsigned*)(lds + OFF_YST + 36 * 1024);
        unsigned* z2 = (unsigned*)(lds + OFF_XST + 36 * 1024);
        for (int i = tid; i < 3072; i += 1024) { z1[i] = 0u; z2[i] = 0u; }
        unsigned* z3 = (unsigned*)(lds + OFF_A1);     // 36864 B contiguous
        for (int i = tid; i < 9216; i += 1024) z3[i] = 0u;
    }
    // ---- stage ysT and xsT (transposed, swizzled, vectorized) ----
    for (int ww = tid; ww < 1152; ww += 1024) {
        int isx = (ww >= 576) ? 1 : 0;
        int u = isx ? (ww - 576) : ww;
        const float* src = isx ? xb : yb;
        char* dst = lds + (isx ? OFF_XST : OFF_YST);
        int dblk = u / 9, s4 = u - dblk * 9;
        int s0 = s4 * 4;
        const float* bp = src + dblk * 8 * T_ + s0;
        u16x8 u0, u1, u2, u3;
        #pragma unroll
        for (int r = 0; r < 8; ++r) {
            f32x4 v = *(const f32x4*)(bp + r * T_);
            u0[r] = f2bf(v[0]); u1[r] = f2bf(v[1]);
            u2[r] = f2bf(v[2]); u3[r] = f2bf(v[3]);
        }
        *(u16x8*)(dst + swz(s0 + 0, dblk * 8)) = u0;
        *(u16x8*)(dst + swz(s0 + 1, dblk * 8)) = u1;
        *(u16x8*)(dst + swz(s0 + 2, dblk * 8)) = u2;
        *(u16x8*)(dst + swz(s0 + 3, dblk * 8)) = u3;
    }
    __syncthreads();

    // ---- Phase 1: G1 (S1[t][s] = tok@y, 12 tiles) + GramT (x^T y, 9 tiles) ----
    for (int tile = w; tile < 21; tile += 16) {
        f32x4 acc = {0.f, 0.f, 0.f, 0.f};
        if (tile < 12) {
            int mt = tile / 3, nt = tile % 3;
            int trow = mt * 16 + l15, srow = nt * 16 + l15;
            for (int ks = 0; ks < 16; ++ks) {
                int k0 = ks * 32 + l4 * 8;
                bf16x8 af = *(const bf16x8*)(tokbf + trow * 512 + k0);
                bf16x8 bv = *(const bf16x8*)(lds + OFF_YST + swz(srow, k0));
                acc = MFMA16(af, bv, acc, 0, 0, 0);
            }
            if (srow < T_) {
                #pragma unroll
                for (int j = 0; j < 4; ++j)
                    sc[(mt * 16 + l4 * 4 + j) * 42 + srow] = acc[j];
            }
        } else {
            int g = tile - 12;
            int mt = g / 3, nt = g % 3;
            int arow = mt * 16 + l15, brow = nt * 16 + l15;
            for (int ks = 0; ks < 16; ++ks) {
                int k0 = ks * 32 + l4 * 8;
                bf16x8 af = *(const bf16x8*)(lds + OFF_XST + swz(arow, k0));
                bf16x8 bv = *(const bf16x8*)(lds + OFF_YST + swz(brow, k0));
                acc = MFMA16(af, bv, acc, 0, 0, 0);
            }
            #pragma unroll
            for (int j = 0; j < 4; ++j)
                gt[(mt * 16 + l4 * 4 + j) * 72 + brow] = f2bf(acc[j]);
        }
    }
    __syncthreads();

    // ---- softmax1 over s per t (writes att1 [t][s] and att1T [s][t]) ----
    {
        int t = tid >> 4, l16 = tid & 15;
        const float* scp = sc + t * 42;
        float v0 = scp[l16];
        float v1 = scp[l16 + 16];
        float v2 = (l16 < 4) ? scp[l16 + 32] : -1e30f;
        float m = fmaxf(fmaxf(v0, v1), v2);
        #pragma unroll
        for (int off = 1; off < 16; off <<= 1) m = fmaxf(m, __shfl_xor(m, off));
        float e0 = __expf(v0 - m), e1 = __expf(v1 - m);
        float e2 = (l16 < 4) ? __expf(v2 - m) : 0.f;
        float ssum = e0 + e1 + e2;
        #pragma unroll
        for (int off = 1; off < 16; off <<= 1) ssum += __shfl_xor(ssum, off);
        float inv = 1.f / ssum;
        unsigned short h0 = f2bf(e0 * inv), h1 = f2bf(e1 * inv);
        a1[t * 72 + l16] = h0;       a1[t * 72 + l16 + 16] = h1;
        a1t[l16 * 72 + t] = h0;      a1t[(l16 + 16) * 72 + t] = h1;
        if (l16 < 4) {
            unsigned short h2 = f2bf(e2 * inv);
            a1[t * 72 + l16 + 32] = h2;
            a1t[(l16 + 32) * 72 + t] = h2;
        }
    }
    __syncthreads();

    // ---- Phase 3: S2[t][s] = tok@x (K=512) + att1@GramT (K=48pad64) ----
    if (w < 12) {
        int mt = w / 3, nt = w % 3;
        int trow = mt * 16 + l15, srow = nt * 16 + l15;
        f32x4 acc = {0.f, 0.f, 0.f, 0.f};
        for (int ks = 0; ks < 16; ++ks) {
            int k0 = ks * 32 + l4 * 8;
            bf16x8 af = *(const bf16x8*)(tokbf + trow * 512 + k0);
            bf16x8 bv = *(const bf16x8*)(lds + OFF_XST + swz(srow, k0));
            acc = MFMA16(af, bv, acc, 0, 0, 0);
        }
        #pragma unroll
        for (int ks = 0; ks < 2; ++ks) {
            int k0 = ks * 32 + l4 * 8;
            bf16x8 af = *(const bf16x8*)(a1 + trow * 72 + k0);
            bf16x8 bv = *(const bf16x8*)(gt + srow * 72 + k0);
            acc = MFMA16(af, bv, acc, 0, 0, 0);
        }
        if (srow < T_) {
            #pragma unroll
            for (int j = 0; j < 4; ++j)
                sc[(mt * 16 + l4 * 4 + j) * 42 + srow] = acc[j];
        }
    }
    __syncthreads();

    // ---- softmax2 over t per s (writes att2 [s][t]) ----
    if (tid < 768) {
        int s = tid >> 4, l16 = tid & 15;
        if (s < T_) {
            float v0 = sc[(l16) * 42 + s];
            float v1 = sc[(l16 + 16) * 42 + s];
            float v2 = sc[(l16 + 32) * 42 + s];
            float v3 = sc[(l16 + 48) * 42 + s];
            float m = fmaxf(fmaxf(v0, v1), fmaxf(v2, v3));
            #pragma unroll
            for (int off = 1; off < 16; off <<= 1) m = fmaxf(m, __shfl_xor(m, off));
            float e0 = __expf(v0 - m), e1 = __expf(v1 - m), e2 = __expf(v2 - m), e3 = __expf(v3 - m);
            float ssum = e0 + e1 + e2 + e3;
            #pragma unroll
            for (int off = 1; off < 16; off <<= 1) ssum += __shfl_xor(ssum, off);
            float inv = 1.f / ssum;
            a2[s * 72 + l16]      = f2bf(e0 * inv);
            a2[s * 72 + l16 + 16] = f2bf(e1 * inv);
            a2[s * 72 + l16 + 32] = f2bf(e2 * inv);
            a2[s * 72 + l16 + 48] = f2bf(e3 * inv);
        }
    }
    __syncthreads();

    // ---- Phase 5: W[s2][s1] = att2 @ att1T  (K=t=64, 9 tiles) ----
    if (w < 9) {
        int mt = w / 3, nt = w % 3;
        f32x4 acc = {0.f, 0.f, 0.f, 0.f};
        #pragma unroll
        for (int ks = 0; ks < 2; ++ks) {
            int k0 = ks * 32 + l4 * 8;
            bf16x8 af = *(const bf16x8*)(a2 + (mt * 16 + l15) * 72 + k0);
            bf16x8 bv = *(const bf16x8*)(a1t + (nt * 16 + l15) * 72 + k0);
            acc = MFMA16(af, bv, acc, 0, 0, 0);
        }
        #pragma unroll
        for (int j = 0; j < 4; ++j)
            wb[(mt * 16 + l4 * 4 + j) * 72 + nt * 16 + l15] = f2bf(acc[j]);
    }
    __syncthreads();

    // ---- Phase 6: xresT[d][s] = tokT@att2 + y@W^T ; xc ; LN -> h_sT ----
    {
        const float gav = gav_p[0];
        f32x4 acc[2][3];
        #pragma unroll
        for (int mi = 0; mi < 2; ++mi)
            #pragma unroll
            for (int n = 0; n < 3; ++n) acc[mi][n] = (f32x4){0.f, 0.f, 0.f, 0.f};

        bf16x8 aT[2][2], aY[2][2];
        #pragma unroll
        for (int mi = 0; mi < 2; ++mi) {
            int d = (2 * w + mi) * 16 + l15;
            aT[mi][0] = *(const bf16x8*)(tokT + d * 64 + l4 * 8);
            aT[mi][1] = *(const bf16x8*)(tokT + d * 64 + 32 + l4 * 8);
            const float* yrow = yb + d * T_;
            f32x4 p0 = *(const f32x4*)(yrow + l4 * 8);
            f32x4 p1 = *(const f32x4*)(yrow + l4 * 8 + 4);
            bf16x8 t0, t1;
            #pragma unroll
            for (int j = 0; j < 4; ++j) { t0[j] = (__bf16)p0[j]; t0[4 + j] = (__bf16)p1[j]; }
            if (l4 == 0) {
                f32x4 p2 = *(const f32x4*)(yrow + 32);
                #pragma unroll
                for (int j = 0; j < 4; ++j) { t1[j] = (__bf16)p2[j]; t1[4 + j] = (__bf16)0.f; }
            } else {
                #pragma unroll
                for (int j = 0; j < 8; ++j) t1[j] = (__bf16)0.f;
            }
            aY[mi][0] = t0; aY[mi][1] = t1;
        }
        #pragma unroll
        for (int n = 0; n < 3; ++n) {
            int srow = n * 16 + l15;
            bf16x8 b20 = *(const bf16x8*)(a2 + srow * 72 + l4 * 8);
            bf16x8 b21 = *(const bf16x8*)(a2 + srow * 72 + 32 + l4 * 8);
            bf16x8 bw0 = *(const bf16x8*)(wb + srow * 72 + l4 * 8);
            bf16x8 bw1 = *(const bf16x8*)(wb + srow * 72 + 32 + l4 * 8);
            #pragma unroll
            for (int mi = 0; mi < 2; ++mi) {
                acc[mi][n] = MFMA16(aT[mi][0], b20, acc[mi][n], 0, 0, 0);
                acc[mi][n] = MFMA16(aT[mi][1], b21, acc[mi][n], 0, 0, 0);
                acc[mi][n] = MFMA16(aY[mi][0], bw0, acc[mi][n], 0, 0, 0);
                acc[mi][n] = MFMA16(aY[mi][1], bw1, acc[mi][n], 0, 0, 0);
            }
        }

        // xc = xs + gav*x_res ; per-s LN partial sums (red overlays dead sc)
        float* red = sc;
        float rs_[3] = {0.f, 0.f, 0.f}, rq_[3] = {0.f, 0.f, 0.f};
        #pragma unroll
        for (int mi = 0; mi < 2; ++mi) {
            #pragma unroll
            for (int n = 0; n < 3; ++n) {
                int s = n * 16 + l15;
                if (s < T_) {
                    #pragma unroll
                    for (int j = 0; j < 4; ++j) {
                        int d = (2 * w + mi) * 16 + l4 * 4 + j;
                        float xsv = bf2f(*(const unsigned short*)(lds + OFF_XST + swz(s, d)));
                        float v = xsv + gav * acc[mi][n][j];
                        acc[mi][n][j] = v;
                        rs_[n] += v; rq_[n] += v * v;
                    }
                }
            }
        }
        #pragma unroll
        for (int n = 0; n < 3; ++n) {
            rs_[n] += __shfl_xor(rs_[n], 16); rq_[n] += __shfl_xor(rq_[n], 16);
            rs_[n] += __shfl_xor(rs_[n], 32); rq_[n] += __shfl_xor(rq_[n], 32);
        }
        if (l4 == 0) {
            #pragma unroll
            for (int n = 0; n < 3; ++n) {
                int s = n * 16 + l15;
                if (s < T_) { red[s * 16 + w] = rs_[n]; red[768 + s * 16 + w] = rq_[n]; }
            }
        }
        __syncthreads();
        if (tid < T_) {
            int s = tid; float S = 0.f, Q = 0.f;
            #pragma unroll
            for (int q = 0; q < 16; ++q) { S += red[s * 16 + q]; Q += red[768 + s * 16 + q]; }
            float mu = S * (1.f / 512.f);
            float var = Q * (1.f / 512.f) - mu * mu;
            red[1536 + s] = mu; red[1584 + s] = rsqrtf(var + EPS_);
        }
        __syncthreads();

        float lg[2][4], lbv[2][4];
        #pragma unroll
        for (int mi = 0; mi < 2; ++mi)
            #pragma unroll
            for (int j = 0; j < 4; ++j) {
                int d = (2 * w + mi) * 16 + l4 * 4 + j;
                lg[mi][j] = lnbg[d]; lbv[mi][j] = lnbb[d];
            }
        #pragma unroll
        for (int mi = 0; mi < 2; ++mi) {
            #pragma unroll
            for (int n = 0; n < 3; ++n) {
                int s = n * 16 + l15;
                if (s < T_) {
                    float mu = red[1536 + s], rsg = red[1584 + s];
                    #pragma unroll
                    for (int j = 0; j < 4; ++j) {
                        int d = (2 * w + mi) * 16 + l4 * 4 + j;
                        *(unsigned short*)(lds + OFF_YST + swz(s, d)) =
                            f2bf((acc[mi][n][j] - mu) * rsg * lg[mi][j] + lbv[mi][j]);
                    }
                }
            }
        }
    }
    __syncthreads();

    // ---- Phase 7: grouped down conv via MFMA: z[o][s] = wdd(blockdiag) @ h_sT ----
    if (w < 6) {
        int mt = w / 3, nt = w % 3;
        int orow = mt * 16 + l15, srow = nt * 16 + l15;
        f32x4 acc = {0.f, 0.f, 0.f, 0.f};
        for (int ks = 0; ks < 16; ++ks) {
            int k0 = ks * 32 + l4 * 8;
            bf16x8 af = *(const bf16x8*)(wdd + orow * 512 + k0);
            bf16x8 bv = *(const bf16x8*)(lds + OFF_YST + swz(srow, k0));
            acc = MFMA16(af, bv, acc, 0, 0, 0);
        }
        if (srow < T_) {
            #pragma unroll
            for (int j = 0; j < 4; ++j)
                z_pre[b * (DS_ * T_) + (mt * 16 + l4 * 4 + j) * T_ + srow] = acc[j];
        }
    }
}

// ---- K3: bn1 stats, two-level ----
__global__ __launch_bounds__(256)
void k3a_bn1part(const float* __restrict__ z_pre, float* __restrict__ p3)
{
    __shared__ float rbuf[4][2];
    int blk = blockIdx.x;
    int o = blk & 31, sl = blk >> 5;
    int tid = threadIdx.x;
    float S = 0.f, Q = 0.f;
    for (int i = tid; i < 64 * T_; i += 256) {
        int bb = sl * 64 + i / T_, t = i - (i / T_) * T_;
        float v = z_pre[bb * (DS_ * T_) + o * T_ + t];
        S += v; Q += v * v;
    }
    #pragma unroll
    for (int off = 1; off < 64; off <<= 1) { S += __shfl_xor(S, off); Q += __shfl_xor(Q, off); }
    int ww = tid >> 6;
    if ((tid & 63) == 0) { rbuf[ww][0] = S; rbuf[ww][1] = Q; }
    __syncthreads();
    if (tid == 0) {
        float s2 = 0.f, q2 = 0.f;
        for (int i = 0; i < 4; ++i) { s2 += rbuf[i][0]; q2 += rbuf[i][1]; }
        p3[blk * 2] = s2; p3[blk * 2 + 1] = q2;
    }
}

__global__ __launch_bounds__(64)
void k3b_bn1stats(const float* __restrict__ p3, float* __restrict__ st1)
{
    int o = threadIdx.x;
    if (o < 32) {
        float S = 0.f, Q = 0.f;
        for (int sl = 0; sl < 16; ++sl) {
            S += p3[((sl << 5) | o) * 2];
            Q += p3[((sl << 5) | o) * 2 + 1];
        }
        float mu = S / 36864.f;
        float var = Q / 36864.f - mu * mu;
        st1[o] = mu; st1[32 + o] = rsqrtf(var + EPS_);
    }
}

// ---- K4M: per-group 8x8 second-moment partials of zr = relu(bn1(z)) ----
__global__ __launch_bounds__(256)
void k4m_moments(const float* __restrict__ z_pre, const float* __restrict__ st1,
                 const float* __restrict__ g1p, const float* __restrict__ b1p,
                 float* __restrict__ m4)
{
    __shared__ float zr[32][40];
    int blk = blockIdx.x, tid = threadIdx.x;
    int c2 = tid & 7, c1 = (tid >> 3) & 7, g = tid >> 6;
    int ch1 = g * 8 + c1, ch2 = g * 8 + c2;
    float acc = 0.f, asum = 0.f;
    for (int bi = 0; bi < 16; ++bi) {
        int b = blk * 16 + bi;
        __syncthreads();
        for (int i = tid; i < DS_ * T_; i += 256) {
            int o = i / T_, t = i - o * T_;
            float v = z_pre[b * (DS_ * T_) + i];
            zr[o][t] = fmaxf(0.f, (v - st1[o]) * st1[32 + o] * g1p[o] + b1p[o]);
        }
        __syncthreads();
        for (int t = 0; t < T_; ++t) {
            float a = zr[ch1][t], b2 = zr[ch2][t];
            acc += a * b2;
            asum += a;
        }
    }
    m4[blk * 288 + tid] = acc;
    if (c1 == c2) m4[blk * 288 + 256 + g * 8 + c1] = asum;
}

// ---- K4S: reduce moments -> bn2 stats via E[o^2] = w^T M w ----
__global__ __launch_bounds__(512)
void k4s_bn2stats(const float* __restrict__ m4, const float* __restrict__ wu,
                  float* __restrict__ st2)
{
    __shared__ float M2[256], mz[32];
    int tid = threadIdx.x;
    if (tid < 256) {
        float S = 0.f;
        for (int k = 0; k < 64; ++k) S += m4[k * 288 + tid];
        M2[tid] = S * (1.f / 36864.f);
    } else if (tid < 288) {
        int j = tid - 256;
        float S = 0.f;
        for (int k = 0; k < 64; ++k) S += m4[k * 288 + 256 + j];
        mz[j] = S * (1.f / 36864.f);
    }
    __syncthreads();
    int d = tid, g = d >> 7;
    float wr[8];
    #pragma unroll
    for (int c = 0; c < 8; ++c) wr[c] = wu[d * 8 + c];
    float mu2 = 0.f;
    #pragma unroll
    for (int c = 0; c < 8; ++c) mu2 += wr[c] * mz[g * 8 + c];
    float e2 = 0.f;
    #pragma unroll
    for (int c = 0; c < 8; ++c)
        #pragma unroll
        for (int c2 = 0; c2 < 8; ++c2)
            e2 += wr[c] * wr[c2] * M2[g * 64 + c * 8 + c2];
    st2[d] = mu2;
    st2[512 + d] = rsqrtf(e2 - mu2 * mu2 + EPS_);
}

// ---- K5: up conv + bn2 + LN(lnp) + gate -> out ----
#define K5_LDS 47888
__global__ __launch_bounds__(512, 6)
void k5_final(const float* __restrict__ z_pre, const float* __restrict__ st1,
              const float* __restrict__ g1p, const float* __restrict__ b1p,
              const float* __restrict__ wu, const float* __restrict__ st2,
              const float* __restrict__ g2p, const float* __restrict__ b2p,
              const float* __restrict__ lnpg, const float* __restrict__ lnpb,
              const float* __restrict__ gate_p, float* __restrict__ out)
{
    extern __shared__ char lds[];
    unsigned short* o_f = (unsigned short*)lds;   // [512][41]
    float* zrT = (float*)(lds + 41984);           // [36][41]
    int b = blockIdx.x;
    int tid = threadIdx.x;

    for (int i = tid; i < DS_ * T_; i += 512) {
        int o = i / T_, s = i - o * T_;
        float v = z_pre[b * (DS_ * T_) + i];
        zrT[s * 41 + o] = fmaxf(0.f, (v - st1[o]) * st1[32 + o] * g1p[o] + b1p[o]);
    }
    __syncthreads();

    for (int i = tid; i < D_ * T_; i += 512) {
        int d = i / T_, t = i - d * T_;
        const float* zp = &zrT[t * 41 + (d >> 7) * 8];
        const float* wp = &wu[d * 8];
        f32x4 w0 = *(const f32x4*)wp;
        f32x4 w1 = *(const f32x4*)(wp + 4);
        float acc = zp[0]*w0[0] + zp[1]*w0[1] + zp[2]*w0[2] + zp[3]*w0[3]
                  + zp[4]*w1[0] + zp[5]*w1[1] + zp[6]*w1[2] + zp[7]*w1[3];
        o_f[d * 41 + t] = f2bf((acc - st2[d]) * st2[512 + d] * g2p[d] + b2p[d]);
    }
    __syncthreads();

    int w = tid >> 6, lane = tid & 63;
    float gate = gate_p[0];
    for (int t = w; t < T_; t += 8) {
        float S = 0.f, Q = 0.f;
        float v[8];
        #pragma unroll
        for (int i2 = 0; i2 < 8; ++i2) {
            float vv = bf2f(o_f[(i2 * 64 + lane) * 41 + t]);
            v[i2] = vv; S += vv; Q += vv * vv;
        }
        #pragma unroll
        for (int off = 1; off < 64; off <<= 1) { S += __shfl_xor(S, off); Q += __shfl_xor(Q, off); }
        float mu = S * (1.f / 512.f);
        float var = Q * (1.f / 512.f) - mu * mu;
        float rs = rsqrtf(var + EPS_);
        #pragma unroll
        for (int i2 = 0; i2 < 8; ++i2) {
            int d = i2 * 64 + lane;
            o_f[d * 41 + t] = f2bf(gate * ((v[i2] - mu) * rs * lnpg[d] + lnpb[d]));
        }
    }
    __syncthreads();

    float* ob = out + b * (D_ * T_);
    for (int i = tid; i < D_ * T_; i += 512) {
        int d = i / T_, t = i - d * T_;
        ob[i] = bf2f(o_f[d * 41 + t]);
    }
}

extern "C" void kernel_launch(void* const* d_in, const int* in_sizes, int n_in,
                              void* d_out, int out_size, void* d_ws, size_t ws_size,
                              hipStream_t stream)
{
    (void)in_sizes; (void)n_in; (void)out_size; (void)ws_size;
    const float* x    = (const float*)d_in[0];
    const float* y    = (const float*)d_in[1];
    const float* tok  = (const float*)d_in[2];
    const float* gate = (const float*)d_in[3];
    const float* gav  = (const float*)d_in[4];
    const float* wd   = (const float*)d_in[5];
    const float* wu   = (const float*)d_in[6];
    const float* bn1g = (const float*)d_in[7];
    const float* bn1b = (const float*)d_in[8];
    const float* bn2g = (const float*)d_in[9];
    const float* bn2b = (const float*)d_in[10];
    const float* lnbg = (const float*)d_in[11];
    const float* lnbb = (const float*)d_in[12];
    const float* lnpg = (const float*)d_in[13];
    const float* lnpb = (const float*)d_in[14];
    float* out = (float*)d_out;

    char* ws = (char*)d_ws;
    float* z_pre          = (float*)ws;                      // 4,718,592
    float* st1            = (float*)(ws + 4718592);          // 512
    unsigned short* tokbf = (unsigned short*)(ws + 4719104); // 65,536
    unsigned short* tokT  = (unsigned short*)(ws + 4784640); // 65,536
    unsigned short* wdd   = (unsigned short*)(ws + 4850176); // 32,768
    float* p3             = (float*)(ws + 4882944);          // 4,096
    float* m4             = (float*)(ws + 4887040);          // 73,728
    float* st2            = (float*)(ws + 4960768);          // 4,096

    hipFuncSetAttribute((const void*)k1_fused, hipFuncAttributeMaxDynamicSharedMemorySize, K1_LDS);
    hipFuncSetAttribute((const void*)k5_final, hipFuncAttributeMaxDynamicSharedMemorySize, K5_LDS);

    k0_prepack<<<160, 512, 0, stream>>>(tok, wd, tokbf, tokT, wdd);
    k1_fused<<<B_, 1024, K1_LDS, stream>>>(x, y, tokbf, tokT, gav, wdd, lnbg, lnbb, z_pre);
    k3a_bn1part<<<512, 256, 0, stream>>>(z_pre, p3);
    k3b_bn1stats<<<1, 64, 0, stream>>>(p3, st1);
    k4m_moments<<<64, 256, 0, stream>>>(z_pre, st1, bn1g, bn1b, m4);
    k4s_bn2stats<<<1, 512, 0, stream>>>(m4, wu, st2);
    k5_final<<<B_, 512, K5_LDS, stream>>>(z_pre, st1, bn1g, bn1b, wu, st2, bn2g, bn2b,
                                          lnpg, lnpb, gate, out);
}